// Round 16
// baseline (47.810 us; speedup 1.0000x reference)
//
#include <hip/hip_runtime.h>
#include <cstdint>
#include <cstddef>

#define Bb 128
#define Cc 64
#define Dd 365
#define Tt 364
#define Ss 32
#define SM1 31
#define NIJ 961
#define BASISF 1e-10f
#define NUNIT 2912         // 46592 bt / 16 rows per wave-unit
#define NBLK 256
#define NWPB 12            // waves per block (768 threads)

typedef _Float16 f16x8 __attribute__((ext_vector_type(8)));
typedef float f32x4 __attribute__((ext_vector_type(4)));

// ---------------------------------------------------------------------------
// Prep: B2 (f16, 65536 = 128 KB):  f16 index = ((c>>3)*1024 + m)*8 + (c&7).
// Column m <-> (i,j) (HW-verified R7-R15):
//   rem=m&255;  i = (m>>8)*8 + (rem>>6)*2 + ((rem&15)>>3);
//   j = 4*(rem&7) + ((rem>>4)&3).
// emu_perm[1024] = exp(-mu), same column permutation.
// ---------------------------------------------------------------------------
__global__ void prep_kernel(const float* __restrict__ mu,
                            const float* __restrict__ beta,
                            _Float16* __restrict__ B2,
                            float* __restrict__ emu_perm) {
    int idx = blockIdx.x * blockDim.x + threadIdx.x;   // 0 .. 65535
    int m = idx >> 6, c = idx & 63;
    int rem = m & 255;
    int i = (m >> 8) * 8 + (rem >> 6) * 2 + ((rem & 15) >> 3);
    int j = 4 * (rem & 7) + ((rem >> 4) & 3);
    float val = (i < SM1 && j < SM1) ? beta[c * NIJ + i * SM1 + j] : 0.0f;
    B2[((size_t)(c >> 3) * 1024 + m) * 8 + (c & 7)] = (_Float16)val;
    if (idx < 1024) {
        int m2 = idx, rem2 = m2 & 255;
        int i2 = (m2 >> 8) * 8 + (rem2 >> 6) * 2 + ((rem2 & 15) >> 3);
        int j2 = 4 * (rem2 & 7) + ((rem2 >> 4) & 3);
        emu_perm[m2] = (i2 < SM1 && j2 < SM1) ? __expf(-mu[i2 * SM1 + j2]) : 1.0f;
    }
}

// ---- DPP helpers (pure VALU cross-lane; no DS pipe) ----
template <int CTRL>
__device__ __forceinline__ float dpp_mov(float x) {
    union { float f; int i; } u, v;
    u.f = x;
    v.i = __builtin_amdgcn_update_dpp(0, u.i, CTRL, 0xf, 0xf, true);
    return v.f;
}
template <int CTRL>
__device__ __forceinline__ float dpp_add(float s) { return s + dpp_mov<CTRL>(s); }
// quad_perm xor1 = 0xB1 ; xor2 = 0x4E ; row_ror:4 = 0x124 ; row_ror:12 = 0x12C
// row_shr:1 = 0x111.  Cross-quad select HW-verified in round 7.

// ---------------------------------------------------------------------------
// 256 blocks x 768 threads (12 waves), 1 block/CU.  ZERO steady-state
// barriers AND 1x A reads (the clean test R12 confounded): each wave owns a
// complete 16-bt-row x 1024-col unit.  A loaded per-wave from global
// (issued BEFORE the prologue barrier, overlapping the B copy), B frags from
// LDS, 16x {8 ds_read_b128, 8 MFMA, DPP epilogue, 4 dwordx4 stores}.
// No Alds, no A-publish, no lockstep - stores free-run to completion.
// ---------------------------------------------------------------------------
__global__ __launch_bounds__(768, 1)
void transition_wave_kernel(const float* __restrict__ adstock,
                            const _Float16* __restrict__ B2,
                            const float* __restrict__ emu_perm,
                            float* __restrict__ out)
{
    const int tid  = threadIdx.x;
    const int lane = tid & 63;
    const int w    = tid >> 6;         // wave 0..11
    const int je   = lane & 15;
    const int grp  = lane >> 4;
    const int a     = je & 7;
    const int ihalf = je >> 3;
    const int j0    = 4 * a;

    __shared__ _Float16 Blds[65536];   // 128 KB
    __shared__ float emuL[1024];       // 4 KB

    // ---- unit for this wave (0 or 1 per wave; contiguous per block) ----
    const int ub = (NUNIT * blockIdx.x) / NBLK;
    const int ue = (NUNIT * (blockIdx.x + 1)) / NBLK;
    const int unit = ub + w;
    const bool active = (unit < ue);

    // ---- A loads issued FIRST (overlap the B-copy + barrier) ----
    float a0f[8], a1f[8];
    if (active) {
        const int bt = unit * 16 + je;
        const int b = bt / Tt, t = bt - b * Tt;
        const float* abase = adstock + ((size_t)b * Cc) * Dd + 1 + t;
        #pragma unroll
        for (int u8 = 0; u8 < 8; ++u8) {
            a0f[u8] = abase[(size_t)(grp * 8 + u8) * Dd];
            a1f[u8] = abase[(size_t)(32 + grp * 8 + u8) * Dd];
        }
    }

    // ---- prologue: B2 + emu -> LDS (linear, coalesced) ----
    for (int o8 = tid * 8; o8 < 65536; o8 += 768 * 8) {
        *reinterpret_cast<f16x8*>(&Blds[o8]) =
            *reinterpret_cast<const f16x8*>(B2 + o8);
    }
    for (int e = tid; e < 1024; e += 768) emuL[e] = emu_perm[e];
    __syncthreads();                   // the ONLY barrier
    if (!active) return;

    f16x8 a0, a1;
    #pragma unroll
    for (int u8 = 0; u8 < 8; ++u8) {
        a0[u8] = (_Float16)a0f[u8];
        a1[u8] = (_Float16)a1f[u8];
    }

    const float m3 = (a == 7) ? 0.0f : 1.0f;   // mask padded j=31 in den
    const int bt0 = unit * 16;
    const size_t rowb = (size_t)(bt0 + grp * 4) * 1024 + j0;

    for (int qq = 0; qq < 4; ++qq) {           // global column quarter
        #pragma unroll
        for (int qp = 0; qp < 4; ++qp) {
            // B frags from LDS: f16 idx = ((kh4*4+grp)*1024 + col)*8
            const int colb = qq * 256 + qp * 64 + je;
            f16x8 Bf[8];
            #pragma unroll
            for (int p = 0; p < 4; ++p) {
                Bf[2 * p]     = *reinterpret_cast<const f16x8*>(
                    &Blds[((0 * 4 + grp) * 1024 + colb + p * 16) * 8]);
                Bf[2 * p + 1] = *reinterpret_cast<const f16x8*>(
                    &Blds[((1 * 4 + grp) * 1024 + colb + p * 16) * 8]);
            }

            float emq[4];
            #pragma unroll
            for (int p = 0; p < 4; ++p)
                emq[p] = emuL[qq * 256 + qp * 64 + p * 16 + je];

            f32x4 acc[4];
            #pragma unroll
            for (int p = 0; p < 4; ++p) {
                f32x4 z = {0.f, 0.f, 0.f, 0.f};
                f32x4 t0 = __builtin_amdgcn_mfma_f32_16x16x32_f16(a0, Bf[2 * p], z, 0, 0, 0);
                acc[p] = __builtin_amdgcn_mfma_f32_16x16x32_f16(a1, Bf[2 * p + 1], t0, 0, 0, 0);
            }

            const int i_lane = qq * 8 + 2 * qp + ihalf;
            const size_t obase = rowb + (size_t)i_lane * 32;

            #pragma unroll
            for (int r = 0; r < 4; ++r) {
                float np[4];
                #pragma unroll
                for (int p = 0; p < 4; ++p) np[p] = __expf(acc[p][r]) * emq[p];

                float s = np[0] + np[1] + fmaf(np[3], m3, np[2]);
                s = dpp_add<0xB1>(s);                  // quad xor1
                s = dpp_add<0x4E>(s);                  // quad xor2
                float t1 = dpp_mov<0x124>(s);          // row_ror:4
                float t2 = dpp_mov<0x12C>(s);          // row_ror:12
                s += (je & 4) ? t1 : t2;               // partner quad (R7-verified)
                const float inv = __builtin_amdgcn_rcpf(1.0f + s);

                const float sh0 = dpp_mov<0x111>(np[3]);
                const float prev[4] = {sh0, np[0], np[1], np[2]};

                float v[4];
                #pragma unroll
                for (int p = 0; p < 4; ++p) {
                    const int j = j0 + p;
                    float x = (j < i_lane) ? np[p] * inv
                            : ((j == i_lane) ? inv : prev[p] * inv);
                    v[p] = fmaxf(x, BASISF);
                }
                if (qq == 3 && qp == 3) {              // absorbing row i=31
                    const bool ab = (i_lane == SM1);
                    v[0] = ab ? BASISF : v[0];
                    v[1] = ab ? BASISF : v[1];
                    v[2] = ab ? BASISF : v[2];
                    v[3] = ab ? ((a == 7) ? (1.0f - SM1 * BASISF) : BASISF) : v[3];
                }
                f32x4 vv = {v[0], v[1], v[2], v[3]};
                *reinterpret_cast<f32x4*>(out + obase + (size_t)r * 1024) = vv;
            }
        }
    }
}

// ---------------------------------------------------------------------------
// Fallback (no workspace): round-1 scalar kernel.
// ---------------------------------------------------------------------------
__global__ __launch_bounds__(256, 4)
void transition_fallback_kernel(const float* __restrict__ adstock,
                                const float* __restrict__ beta,
                                const float* __restrict__ mu,
                                float* __restrict__ out) {
    const int b  = blockIdx.x;
    const int t0 = blockIdx.y * 16;
    const int tid = threadIdx.x;

    __shared__ float adT[Cc][16];
    __shared__ float num_lds[8][964];

    for (int k = tid; k < Cc * 16; k += 256) {
        int c = k >> 4, tt = k & 15, t = t0 + tt;
        adT[c][tt] = (t < Tt) ? adstock[(size_t)b * (Cc * Dd) + c * Dd + 1 + t] : 0.0f;
    }
    __syncthreads();

    const int ij0 = tid * 4;
    const bool active = (ij0 < 964);
    float acc[16][4];
    #pragma unroll
    for (int tt = 0; tt < 16; ++tt) { acc[tt][0]=0;acc[tt][1]=0;acc[tt][2]=0;acc[tt][3]=0; }

    if (active) {
        for (int c = 0; c < Cc; ++c) {
            const float* bsrc = beta + (size_t)c * NIJ;
            float w0 = (ij0+0<NIJ)?bsrc[ij0+0]:0.f, w1 = (ij0+1<NIJ)?bsrc[ij0+1]:0.f;
            float w2 = (ij0+2<NIJ)?bsrc[ij0+2]:0.f, w3 = (ij0+3<NIJ)?bsrc[ij0+3]:0.f;
            #pragma unroll
            for (int tt = 0; tt < 16; ++tt) {
                float av = adT[c][tt];
                acc[tt][0] = fmaf(av, w0, acc[tt][0]);
                acc[tt][1] = fmaf(av, w1, acc[tt][1]);
                acc[tt][2] = fmaf(av, w2, acc[tt][2]);
                acc[tt][3] = fmaf(av, w3, acc[tt][3]);
            }
        }
    }
    float m0=0,m1=0,m2=0,m3=0;
    if (active) {
        m0 = (ij0+0<NIJ)?mu[ij0+0]:0.f; m1 = (ij0+1<NIJ)?mu[ij0+1]:0.f;
        m2 = (ij0+2<NIJ)?mu[ij0+2]:0.f; m3 = (ij0+3<NIJ)?mu[ij0+3]:0.f;
    }
    const int q8 = tid >> 5, irow = tid & 31;
    #pragma unroll
    for (int half = 0; half < 2; ++half) {
        if (active) {
            #pragma unroll
            for (int q = 0; q < 8; ++q) {
                const int tt = half * 8 + q;
                num_lds[q][ij0+0] = __expf(acc[tt][0] - m0);
                num_lds[q][ij0+1] = __expf(acc[tt][1] - m1);
                num_lds[q][ij0+2] = __expf(acc[tt][2] - m2);
                num_lds[q][ij0+3] = __expf(acc[tt][3] - m3);
            }
        }
        __syncthreads();
        const int t = t0 + half * 8 + q8;
        if (t < Tt) {
            float* op = out + (((size_t)b * Tt + t) * Ss + irow) * Ss;
            if (irow < SM1) {
                float row[SM1]; float den = 1.0f;
                #pragma unroll
                for (int j = 0; j < SM1; ++j) { row[j] = num_lds[q8][irow*SM1+j]; den += row[j]; }
                const float inv = 1.0f / den;
                #pragma unroll
                for (int j = 0; j < Ss; ++j) {
                    float vv = (j < irow) ? row[j]*inv : ((j == irow) ? inv
                              : (j-1 < SM1 ? row[j-1]*inv : 0.f));
                    op[j] = fmaxf(vv, BASISF);
                }
            } else {
                #pragma unroll
                for (int j = 0; j < Ss; ++j) op[j] = (j == SM1) ? (1.0f - SM1*BASISF) : BASISF;
            }
        }
        __syncthreads();
    }
}

// ---------------------------------------------------------------------------
extern "C" void kernel_launch(void* const* d_in, const int* in_sizes, int n_in,
                              void* d_out, int out_size, void* d_ws, size_t ws_size,
                              hipStream_t stream) {
    const float* adstock = (const float*)d_in[0];
    const float* mu      = (const float*)d_in[1];
    const float* beta    = (const float*)d_in[2];
    float* out = (float*)d_out;

    const size_t need = (size_t)65536 * sizeof(_Float16) + 1024 * sizeof(float);

    if (ws_size >= need) {
        _Float16* B2 = (_Float16*)d_ws;
        float* emu_perm = (float*)((char*)d_ws + (size_t)65536 * sizeof(_Float16));
        prep_kernel<<<(1024 * Cc) / 256, 256, 0, stream>>>(mu, beta, B2, emu_perm);
        transition_wave_kernel<<<NBLK, 768, 0, stream>>>(adstock, B2, emu_perm, out);
    } else {
        dim3 grid(Bb, (Tt + 15) / 16);
        transition_fallback_kernel<<<grid, 256, 0, stream>>>(adstock, beta, mu, out);
    }
}

// Round 17
// 43.612 us; speedup vs baseline: 1.0963x; 1.0963x over previous
//
#include <hip/hip_runtime.h>
#include <cstdint>
#include <cstddef>

#define Bb 128
#define Cc 64
#define Dd 365
#define Tt 364
#define Ss 32
#define SM1 31
#define NIJ 961
#define BASISF 1e-10f
#define NTILES 728         // 46592 bt / 64 per tile
#define NBLK 256           // persistent blocks, 1 per CU

typedef _Float16 f16x8 __attribute__((ext_vector_type(8)));
typedef _Float16 f16x4 __attribute__((ext_vector_type(4)));
typedef float f32x4 __attribute__((ext_vector_type(4)));

// ---------------------------------------------------------------------------
// Prep: B2 (f16, 65536 = 128 KB) in the LDS layout
//   f16 index = ((c>>3)*1024 + m)*8 + (c&7)
// Column m <-> (i,j) mapping (HW-verified R7-R16):
//   rem=m&255;  i = (m>>8)*8 + (rem>>6)*2 + ((rem&15)>>3);
//   j = 4*(rem&7) + ((rem>>4)&3).
// emu_perm[1024] = exp(-mu) in the same column permutation.
// ---------------------------------------------------------------------------
__global__ void prep_kernel(const float* __restrict__ mu,
                            const float* __restrict__ beta,
                            _Float16* __restrict__ B2,
                            float* __restrict__ emu_perm) {
    int idx = blockIdx.x * blockDim.x + threadIdx.x;   // 0 .. 65535
    int m = idx >> 6, c = idx & 63;
    int rem = m & 255;
    int i = (m >> 8) * 8 + (rem >> 6) * 2 + ((rem & 15) >> 3);
    int j = 4 * (rem & 7) + ((rem >> 4) & 3);
    float val = (i < SM1 && j < SM1) ? beta[c * NIJ + i * SM1 + j] : 0.0f;
    B2[((size_t)(c >> 3) * 1024 + m) * 8 + (c & 7)] = (_Float16)val;
    if (idx < 1024) {
        int m2 = idx, rem2 = m2 & 255;
        int i2 = (m2 >> 8) * 8 + (rem2 >> 6) * 2 + ((rem2 & 15) >> 3);
        int j2 = 4 * (rem2 & 7) + ((rem2 >> 4) & 3);
        emu_perm[m2] = (i2 < SM1 && j2 < SM1) ? __expf(-mu[i2 * SM1 + j2]) : 1.0f;
    }
}

// ---- DPP helpers (pure VALU cross-lane; no DS pipe) ----
template <int CTRL>
__device__ __forceinline__ float dpp_mov(float x) {
    union { float f; int i; } u, v;
    u.f = x;
    v.i = __builtin_amdgcn_update_dpp(0, u.i, CTRL, 0xf, 0xf, true);
    return v.f;
}
template <int CTRL>
__device__ __forceinline__ float dpp_add(float s) { return s + dpp_mov<CTRL>(s); }
// quad_perm xor1 = 0xB1 ; xor2 = 0x4E ; row_ror:4 = 0x124 ; row_ror:12 = 0x12C
// row_shr:1 = 0x111.  Cross-quad select HW-verified in round 7.

// ---------------------------------------------------------------------------
// Persistent kernel (R10, best measured 43.6 us): 256 blocks x 1024 threads
// (16 waves), 1 block/CU.
// Prologue: linear coalesced copy of B2 (128 KB) into LDS; emu -> 16 regs.
// Per 64-bt tile (two-barrier, replay-stable single A buffer):
//   barrier; ds_write A(tile) from regs; barrier;
//   prefetch A(tile+1) -> regs;  compute (LDS B frags + MFMA + DPP epilogue
//   + dwordx4 stores).
// ---------------------------------------------------------------------------
__global__ __launch_bounds__(1024, 1)
void transition_persist_kernel(const float* __restrict__ adstock,
                               const _Float16* __restrict__ B2,
                               const float* __restrict__ emu_perm,
                               float* __restrict__ out)
{
    const int tid  = threadIdx.x;
    const int lane = tid & 63;
    const int w    = tid >> 6;         // wave 0..15
    const int je   = lane & 15;
    const int grp  = lane >> 4;
    const int mh   = w >> 2;           // bt quarter (16 rows each)
    const int nq   = w & 3;            // column quarter = i-rows nq*8..+7
    const int a     = je & 7;
    const int ihalf = je >> 3;
    const int j0    = 4 * a;

    __shared__ _Float16 Blds[65536];                // 128 KB
    __shared__ __align__(16) _Float16 Alds[64][72]; // 9 KB (144 B rows)

    // ---- B: global -> LDS, linear coalesced copy (8 sweeps x 16 B) ----
    #pragma unroll
    for (int s = 0; s < 8; ++s) {
        const int o8 = s * 8192 + tid * 8;          // f16 units
        *reinterpret_cast<f16x8*>(&Blds[o8]) =
            *reinterpret_cast<const f16x8*>(B2 + o8);
    }

    // ---- emu -> 16 registers per lane ----
    float emu[4][4];
    #pragma unroll
    for (int qp = 0; qp < 4; ++qp)
        #pragma unroll
        for (int p = 0; p < 4; ++p)
            emu[qp][p] = emu_perm[nq * 256 + qp * 64 + p * 16 + je];

    const float m3 = (a == 7) ? 0.0f : 1.0f;        // mask padded j=31

    // ---- tile range for this block ----
    const int tb = (NTILES * blockIdx.x) / NBLK;
    const int te = (NTILES * (blockIdx.x + 1)) / NBLK;

    // ---- A staging indices (per thread): 64 rows x 16 c-groups ----
    const int m_s = tid >> 4;          // 0..63 bt-row within tile
    const int c0  = (tid & 15) * 4;    // 4 consecutive camps

    // prefetch A(tb) into registers
    float av0, av1, av2, av3;
    {
        const int bt = tb * 64 + m_s;
        const int b = bt / Tt, t = bt - b * Tt;
        av0 = adstock[((size_t)b * Cc + c0 + 0) * Dd + 1 + t];
        av1 = adstock[((size_t)b * Cc + c0 + 1) * Dd + 1 + t];
        av2 = adstock[((size_t)b * Cc + c0 + 2) * Dd + 1 + t];
        av3 = adstock[((size_t)b * Cc + c0 + 3) * Dd + 1 + t];
    }

    for (int tile = tb; tile < te; ++tile) {
        // ---- publish A(tile); barriers isolate reads from writes ----
        __syncthreads();   // all prior-tile reads of Alds complete
        {
            f16x4 pk = {(_Float16)av0, (_Float16)av1, (_Float16)av2, (_Float16)av3};
            *reinterpret_cast<f16x4*>(&Alds[m_s][c0]) = pk;
        }
        __syncthreads();   // A(tile) visible to all waves (Blds ready on 1st iter)

        // ---- prefetch A(tile+1) into regs (latency hidden under compute) ----
        if (tile + 1 < te) {
            const int bt = (tile + 1) * 64 + m_s;
            const int b = bt / Tt, t = bt - b * Tt;
            av0 = adstock[((size_t)b * Cc + c0 + 0) * Dd + 1 + t];
            av1 = adstock[((size_t)b * Cc + c0 + 1) * Dd + 1 + t];
            av2 = adstock[((size_t)b * Cc + c0 + 2) * Dd + 1 + t];
            av3 = adstock[((size_t)b * Cc + c0 + 3) * Dd + 1 + t];
        }

        // ---- compute current tile ----
        const f16x8 a0 = *reinterpret_cast<const f16x8*>(&Alds[mh * 16 + je][grp * 8]);
        const f16x8 a1 = *reinterpret_cast<const f16x8*>(&Alds[mh * 16 + je][32 + grp * 8]);

        const int bt0 = tile * 64 + mh * 16;

        #pragma unroll
        for (int qp = 0; qp < 4; ++qp) {
            // B frags from LDS: f16 idx = ((kh4*4+grp)*1024 + col)*8
            const int colb = nq * 256 + qp * 64 + je;
            f16x8 Bf[8];
            #pragma unroll
            for (int p = 0; p < 4; ++p) {
                Bf[2 * p]     = *reinterpret_cast<const f16x8*>(
                    &Blds[((0 * 4 + grp) * 1024 + colb + p * 16) * 8]);
                Bf[2 * p + 1] = *reinterpret_cast<const f16x8*>(
                    &Blds[((1 * 4 + grp) * 1024 + colb + p * 16) * 8]);
            }

            f32x4 acc[4];
            #pragma unroll
            for (int p = 0; p < 4; ++p) {
                f32x4 z = {0.f, 0.f, 0.f, 0.f};
                f32x4 t0 = __builtin_amdgcn_mfma_f32_16x16x32_f16(a0, Bf[2 * p], z, 0, 0, 0);
                acc[p] = __builtin_amdgcn_mfma_f32_16x16x32_f16(a1, Bf[2 * p + 1], t0, 0, 0, 0);
            }

            const int i_lane = nq * 8 + 2 * qp + ihalf;
            const size_t obase = (size_t)(bt0 + grp * 4) * 1024
                               + (size_t)i_lane * 32 + j0;

            #pragma unroll
            for (int r = 0; r < 4; ++r) {
                float np[4];
                #pragma unroll
                for (int p = 0; p < 4; ++p) np[p] = __expf(acc[p][r]) * emu[qp][p];

                float s = np[0] + np[1] + fmaf(np[3], m3, np[2]);
                s = dpp_add<0xB1>(s);                  // quad xor1
                s = dpp_add<0x4E>(s);                  // quad xor2
                float t1 = dpp_mov<0x124>(s);          // row_ror:4
                float t2 = dpp_mov<0x12C>(s);          // row_ror:12
                s += (je & 4) ? t1 : t2;               // partner quad (R7-verified)
                const float inv = __builtin_amdgcn_rcpf(1.0f + s);

                const float sh0 = dpp_mov<0x111>(np[3]);
                const float prev[4] = {sh0, np[0], np[1], np[2]};

                float v[4];
                #pragma unroll
                for (int p = 0; p < 4; ++p) {
                    const int j = j0 + p;
                    float x = (j < i_lane) ? np[p] * inv
                            : ((j == i_lane) ? inv : prev[p] * inv);
                    v[p] = fmaxf(x, BASISF);
                }
                if (nq == 3 && qp == 3) {              // absorbing row i=31
                    const bool ab = (i_lane == SM1);
                    v[0] = ab ? BASISF : v[0];
                    v[1] = ab ? BASISF : v[1];
                    v[2] = ab ? BASISF : v[2];
                    v[3] = ab ? ((a == 7) ? (1.0f - SM1 * BASISF) : BASISF) : v[3];
                }
                f32x4 vv = {v[0], v[1], v[2], v[3]};
                *reinterpret_cast<f32x4*>(out + obase + (size_t)r * 1024) = vv;
            }
        }
    }
}

// ---------------------------------------------------------------------------
// Fallback (no workspace): round-1 scalar kernel.
// ---------------------------------------------------------------------------
__global__ __launch_bounds__(256, 4)
void transition_fallback_kernel(const float* __restrict__ adstock,
                                const float* __restrict__ beta,
                                const float* __restrict__ mu,
                                float* __restrict__ out) {
    const int b  = blockIdx.x;
    const int t0 = blockIdx.y * 16;
    const int tid = threadIdx.x;

    __shared__ float adT[Cc][16];
    __shared__ float num_lds[8][964];

    for (int k = tid; k < Cc * 16; k += 256) {
        int c = k >> 4, tt = k & 15, t = t0 + tt;
        adT[c][tt] = (t < Tt) ? adstock[(size_t)b * (Cc * Dd) + c * Dd + 1 + t] : 0.0f;
    }
    __syncthreads();

    const int ij0 = tid * 4;
    const bool active = (ij0 < 964);
    float acc[16][4];
    #pragma unroll
    for (int tt = 0; tt < 16; ++tt) { acc[tt][0]=0;acc[tt][1]=0;acc[tt][2]=0;acc[tt][3]=0; }

    if (active) {
        for (int c = 0; c < Cc; ++c) {
            const float* bsrc = beta + (size_t)c * NIJ;
            float w0 = (ij0+0<NIJ)?bsrc[ij0+0]:0.f, w1 = (ij0+1<NIJ)?bsrc[ij0+1]:0.f;
            float w2 = (ij0+2<NIJ)?bsrc[ij0+2]:0.f, w3 = (ij0+3<NIJ)?bsrc[ij0+3]:0.f;
            #pragma unroll
            for (int tt = 0; tt < 16; ++tt) {
                float av = adT[c][tt];
                acc[tt][0] = fmaf(av, w0, acc[tt][0]);
                acc[tt][1] = fmaf(av, w1, acc[tt][1]);
                acc[tt][2] = fmaf(av, w2, acc[tt][2]);
                acc[tt][3] = fmaf(av, w3, acc[tt][3]);
            }
        }
    }
    float m0=0,m1=0,m2=0,m3=0;
    if (active) {
        m0 = (ij0+0<NIJ)?mu[ij0+0]:0.f; m1 = (ij0+1<NIJ)?mu[ij0+1]:0.f;
        m2 = (ij0+2<NIJ)?mu[ij0+2]:0.f; m3 = (ij0+3<NIJ)?mu[ij0+3]:0.f;
    }
    const int q8 = tid >> 5, irow = tid & 31;
    #pragma unroll
    for (int half = 0; half < 2; ++half) {
        if (active) {
            #pragma unroll
            for (int q = 0; q < 8; ++q) {
                const int tt = half * 8 + q;
                num_lds[q][ij0+0] = __expf(acc[tt][0] - m0);
                num_lds[q][ij0+1] = __expf(acc[tt][1] - m1);
                num_lds[q][ij0+2] = __expf(acc[tt][2] - m2);
                num_lds[q][ij0+3] = __expf(acc[tt][3] - m3);
            }
        }
        __syncthreads();
        const int t = t0 + half * 8 + q8;
        if (t < Tt) {
            float* op = out + (((size_t)b * Tt + t) * Ss + irow) * Ss;
            if (irow < SM1) {
                float row[SM1]; float den = 1.0f;
                #pragma unroll
                for (int j = 0; j < SM1; ++j) { row[j] = num_lds[q8][irow*SM1+j]; den += row[j]; }
                const float inv = 1.0f / den;
                #pragma unroll
                for (int j = 0; j < Ss; ++j) {
                    float vv = (j < irow) ? row[j]*inv : ((j == irow) ? inv
                              : (j-1 < SM1 ? row[j-1]*inv : 0.f));
                    op[j] = fmaxf(vv, BASISF);
                }
            } else {
                #pragma unroll
                for (int j = 0; j < Ss; ++j) op[j] = (j == SM1) ? (1.0f - SM1*BASISF) : BASISF;
            }
        }
        __syncthreads();
    }
}

// ---------------------------------------------------------------------------
extern "C" void kernel_launch(void* const* d_in, const int* in_sizes, int n_in,
                              void* d_out, int out_size, void* d_ws, size_t ws_size,
                              hipStream_t stream) {
    const float* adstock = (const float*)d_in[0];
    const float* mu      = (const float*)d_in[1];
    const float* beta    = (const float*)d_in[2];
    float* out = (float*)d_out;

    const size_t need = (size_t)65536 * sizeof(_Float16) + 1024 * sizeof(float);

    if (ws_size >= need) {
        _Float16* B2 = (_Float16*)d_ws;
        float* emu_perm = (float*)((char*)d_ws + (size_t)65536 * sizeof(_Float16));
        prep_kernel<<<(1024 * Cc) / 256, 256, 0, stream>>>(mu, beta, B2, emu_perm);
        transition_persist_kernel<<<NBLK, 1024, 0, stream>>>(adstock, B2, emu_perm, out);
    } else {
        dim3 grid(Bb, (Tt + 15) / 16);
        transition_fallback_kernel<<<grid, 256, 0, stream>>>(adstock, beta, mu, out);
    }
}